// Round 11
// baseline (441.583 us; speedup 1.0000x reference)
//
#include <hip/hip_runtime.h>
#include <math.h>

typedef unsigned short u16;
typedef unsigned int u32;
typedef _Float16 f16;
typedef __attribute__((ext_vector_type(8))) short bf16x8;
typedef __attribute__((ext_vector_type(8))) _Float16 f16x8;
typedef __attribute__((ext_vector_type(4))) float f32x4;

constexpr int Bc = 32, Nc = 1024, Cc = 768, Hc = 12, HDc = 64, Mc = 128;
constexpr int NUM_STEP_C = 8;
constexpr float QSCALE = 0.35355339059327376f;      // 8^-0.5
constexpr float INV_SQRT_M = 0.088388347648318447f; // 1/sqrt(128)
constexpr float EPSC = 1e-12f;
constexpr int FS = 136;  // f16 LDS row stride (16B-aligned, banks +4 mod 32)

#define BAR_RAW() asm volatile("s_barrier" ::: "memory")
#define WAIT_VM(N) asm volatile("s_waitcnt vmcnt(" #N ")" ::: "memory")

__device__ __forceinline__ float softf(float z, float thr) {
  float az = fabsf(z) - thr;
  float g = 0.5f * az * (1.0f + erff(az * 0.70710678118654752f));
  return (z > 0.f) ? g : ((z < 0.f) ? -g : 0.f);
}

__device__ __forceinline__ u16 f2bf(float f) {
  u32 u = __float_as_uint(f);
  u += 0x7fffu + ((u >> 16) & 1u);
  return (u16)(u >> 16);
}

__device__ __forceinline__ f32x4 fzero() {
  f32x4 z; z[0] = 0.f; z[1] = 0.f; z[2] = 0.f; z[3] = 0.f; return z;
}

__device__ __forceinline__ f32x4 mfma16(bf16x8 a, bf16x8 b, f32x4 c) {
  return __builtin_amdgcn_mfma_f32_16x16x32_bf16(a, b, c, 0, 0, 0);
}
__device__ __forceinline__ f32x4 mfma16h(f16x8 a, f16x8 b, f32x4 c) {
  return __builtin_amdgcn_mfma_f32_16x16x32_f16(a, b, c, 0, 0, 0);
}

// Swizzled read offset within a [*][64]-u16 LDS tile: col(u16) XOR'ed by row
#define SWZ_COL(col, row) ((col) ^ (((row) & 7) << 3))

// Stage 32 rows x 64 u16 of a row-major (ld elems) global tile into linear
// LDS [.][64]; inverse swizzle pre-applied to the GLOBAL source (rule #21).
// 4 global_load_lds per wave per call.
__device__ __forceinline__ void stage_swz(const u16* __restrict__ g, int ld,
                                          u16* lds, int w, int lane) {
  const int rr = lane >> 3;                 // 0..7 row within 8-row call
  const int cs = ((lane & 7) ^ rr) << 3;    // pre-swizzled col (u16)
#pragma unroll
  for (int c = 0; c < 4; ++c) {
    const int r0 = w * 32 + c * 8;
    __builtin_amdgcn_global_load_lds(
        (const __attribute__((address_space(1))) void*)(g + (size_t)(r0 + rr) * ld + cs),
        (__attribute__((address_space(3))) void*)(lds + r0 * 64), 16, 0, 0);
  }
}

// ---------------------------------------------------------------------------
// prep: f32 -> bf16 (x, qkv_w, proj_w), rand_matrix transpose, and
// learned_k -> fp16 (direct + transposed)
// ---------------------------------------------------------------------------
__global__ __launch_bounds__(256) void prep_kernel(
    const float* __restrict__ x, const float* __restrict__ qw,
    const float* __restrict__ pw, const float* __restrict__ rnd,
    const float* __restrict__ lkf, u16* __restrict__ xbf,
    u16* __restrict__ wbf, u16* __restrict__ pwbf, u16* __restrict__ randt,
    f16* __restrict__ lk16, f16* __restrict__ lkT16) {
  const int NX8 = 3145728, NW8 = 147456, NP8 = 73728, NR = 98304;
  const int NK8 = 2048, NKT = 16384;
  const int total = NX8 + NW8 + NP8 + NR + NK8 + NKT;
  for (int idx = blockIdx.x * 256 + threadIdx.x; idx < total;
       idx += gridDim.x * 256) {
    if (idx < NX8 + NW8 + NP8) {
      const float* src; u16* dst; int k;
      if (idx < NX8) { src = x; dst = xbf; k = idx; }
      else if (idx < NX8 + NW8) { src = qw; dst = wbf; k = idx - NX8; }
      else { src = pw; dst = pwbf; k = idx - NX8 - NW8; }
      float4 a = *(const float4*)(src + (size_t)k * 8);
      float4 b = *(const float4*)(src + (size_t)k * 8 + 4);
      uint4 o;
      o.x = (u32)f2bf(a.x) | ((u32)f2bf(a.y) << 16);
      o.y = (u32)f2bf(a.z) | ((u32)f2bf(a.w) << 16);
      o.z = (u32)f2bf(b.x) | ((u32)f2bf(b.y) << 16);
      o.w = (u32)f2bf(b.z) | ((u32)f2bf(b.w) << 16);
      *(uint4*)(dst + (size_t)k * 8) = o;
    } else if (idx < NX8 + NW8 + NP8 + NR) {
      int k = idx - NX8 - NW8 - NP8;           // rand_t[h][m][d]
      int h = k >> 13, rem = k & 8191, m = rem >> 6, d = rem & 63;
      randt[k] = f2bf(rnd[(size_t)h * 8192 + d * 128 + m]);
    } else if (idx < NX8 + NW8 + NP8 + NR + NK8) {
      int k = idx - (NX8 + NW8 + NP8 + NR);    // 8-wide fp16 convert
      float4 a = *(const float4*)(lkf + (size_t)k * 8);
      float4 b = *(const float4*)(lkf + (size_t)k * 8 + 4);
      union { f16 h[8]; uint4 u; } z;
      z.h[0] = (f16)a.x; z.h[1] = (f16)a.y; z.h[2] = (f16)a.z; z.h[3] = (f16)a.w;
      z.h[4] = (f16)b.x; z.h[5] = (f16)b.y; z.h[6] = (f16)b.z; z.h[7] = (f16)b.w;
      *(uint4*)(lk16 + (size_t)k * 8) = z.u;
    } else {
      int k = idx - (NX8 + NW8 + NP8 + NR + NK8);  // lkT16[c][p] = lk[p][c]
      int c = k >> 7, p = k & 127;
      lkT16[k] = (f16)lkf[p * 128 + c];
    }
  }
}

// ---------------------------------------------------------------------------
// Fused QKV MFMA GEMM + qf epilogue. BK=64, SINGLE-buffered (36 KB LDS ->
// 4 blocks/CU; inter-block wave overlap hides the barrier drain, m114/m97).
// XCD-swizzled grid. bj<6: q -> qf_t; bj>=6: v -> vb_t.
// ---------------------------------------------------------------------------
__global__ __launch_bounds__(256) void qkv_qf_kernel(
    const u16* __restrict__ xbf, const u16* __restrict__ wbf,
    const u16* __restrict__ randt, u16* __restrict__ qft,
    u16* __restrict__ vbt) {
  // Als[128*64] | Bls[128*64] (32 KB); epilogue reuses as Qls[2][128][72]
  __shared__ __align__(16) u16 SH[18432];
  u16* Als = SH;
  u16* Bls = SH + 8192;
  const int t = threadIdx.x;
  const int hblk = blockIdx.x;
  const int lin = (hblk & 7) * 384 + (hblk >> 3);
  const int bi = lin / 12, bj = lin % 12;
  const int w = t >> 6, lane = t & 63, ln = lane & 15, kg = lane >> 4;
  const int wr = w >> 1, wc = w & 1;
  f32x4 acc[4][4];
#pragma unroll
  for (int i = 0; i < 4; ++i)
#pragma unroll
    for (int j = 0; j < 4; ++j) acc[i][j] = fzero();
  const u16* Ag = xbf + (size_t)(bi * 128) * Cc;
  const u16* Bg = wbf + (size_t)(bj * 128) * Cc;
  for (int k0 = 0; k0 < Cc; k0 += 64) {
    stage_swz(Ag + k0, Cc, Als, w, lane);
    stage_swz(Bg + k0, Cc, Bls, w, lane);
    __syncthreads();
#pragma unroll
    for (int ks = 0; ks < 2; ++ks) {
      const int cb = ks * 32 + kg * 8;
      bf16x8 af[4], bf[4];
#pragma unroll
      for (int i = 0; i < 4; ++i)
        af[i] = *(const bf16x8*)(Als + (wr * 64 + i * 16 + ln) * 64 +
                                 SWZ_COL(cb, ln));
#pragma unroll
      for (int j = 0; j < 4; ++j)
        bf[j] = *(const bf16x8*)(Bls + (wc * 64 + j * 16 + ln) * 64 +
                                 SWZ_COL(cb, ln));
#pragma unroll
      for (int i = 0; i < 4; ++i)
#pragma unroll
        for (int j = 0; j < 4; ++j) acc[i][j] = mfma16(af[i], bf[j], acc[i][j]);
    }
    __syncthreads();
  }
  const int b = bi >> 3;
  const int ntile = (bi & 7) * 128;
  if (bj >= 6) {
    const int h = (bj - 6) * 2 + wc;
    u16* vt = vbt + ((size_t)(b * Hc + h) * 64) * 1024;
#pragma unroll
    for (int i = 0; i < 4; ++i)
#pragma unroll
      for (int j = 0; j < 4; ++j) {
        int d = j * 16 + ln;
        int n0 = ntile + wr * 64 + i * 16 + kg * 4;
        uint2 pv;
        pv.x = (u32)f2bf(acc[i][j][0]) | ((u32)f2bf(acc[i][j][1]) << 16);
        pv.y = (u32)f2bf(acc[i][j][2]) | ((u32)f2bf(acc[i][j][3]) << 16);
        *(uint2*)(vt + (size_t)d * 1024 + n0) = pv;
      }
  } else {
#pragma unroll
    for (int i = 0; i < 4; ++i)
#pragma unroll
      for (int j = 0; j < 4; ++j) acc[i][j] *= QSCALE;
    float hn[4][4];
#pragma unroll
    for (int i = 0; i < 4; ++i)
#pragma unroll
      for (int r = 0; r < 4; ++r) {
        float s = acc[i][0][r] * acc[i][0][r] + acc[i][1][r] * acc[i][1][r] +
                  acc[i][2][r] * acc[i][2][r] + acc[i][3][r] * acc[i][3][r];
        s += __shfl_xor(s, 1); s += __shfl_xor(s, 2);
        s += __shfl_xor(s, 4); s += __shfl_xor(s, 8);
        hn[i][r] = 0.5f * s;
      }
    u16* Qls = SH;
#pragma unroll
    for (int i = 0; i < 4; ++i)
#pragma unroll
      for (int j = 0; j < 4; ++j)
#pragma unroll
        for (int r = 0; r < 4; ++r)
          Qls[(size_t)(wc * 128 + wr * 64 + i * 16 + kg * 4 + r) * 72 +
              j * 16 + ln] = f2bf(acc[i][j][r]);
    __syncthreads();
    const int hq = bj * 2 + (w & 1);
    const int r0q = (w >> 1) * 64;
    const u16* rt = randt + (size_t)hq * Mc * HDc;  // [m][64]
    u16* qtb = qft + ((size_t)(b * Hc + hq) * Mc) * Nc;  // [m][n]
    const u16* qsl = Qls + (size_t)(w & 1) * 128 * 72;
#pragma unroll
    for (int mh = 0; mh < 2; ++mh) {
      f32x4 a2[4][4];
#pragma unroll
      for (int i = 0; i < 4; ++i)
#pragma unroll
        for (int j = 0; j < 4; ++j) a2[i][j] = fzero();
#pragma unroll
      for (int ks = 0; ks < 2; ++ks) {
        bf16x8 af[4], bfr[4];
#pragma unroll
        for (int i = 0; i < 4; ++i)
          af[i] = *(const bf16x8*)(qsl + (size_t)(r0q + i * 16 + ln) * 72 +
                                   ks * 32 + kg * 8);
#pragma unroll
        for (int j = 0; j < 4; ++j)
          bfr[j] = *(const bf16x8*)(rt +
                                    (size_t)(mh * 64 + j * 16 + ln) * 64 +
                                    ks * 32 + kg * 8);
#pragma unroll
        for (int i = 0; i < 4; ++i)
#pragma unroll
          for (int j = 0; j < 4; ++j)
            a2[i][j] = mfma16(af[i], bfr[j], a2[i][j]);
      }
#pragma unroll
      for (int i = 0; i < 4; ++i)
#pragma unroll
        for (int j = 0; j < 4; ++j) {
          const int m = mh * 64 + j * 16 + ln;
          const int n0 = ntile + r0q + i * 16 + kg * 4;
          float e0 = __expf(a2[i][j][0] - hn[i][0]) * INV_SQRT_M;
          float e1 = __expf(a2[i][j][1] - hn[i][1]) * INV_SQRT_M;
          float e2 = __expf(a2[i][j][2] - hn[i][2]) * INV_SQRT_M;
          float e3 = __expf(a2[i][j][3] - hn[i][3]) * INV_SQRT_M;
          uint2 pv;
          pv.x = (u32)f2bf(e0) | ((u32)f2bf(e1) << 16);
          pv.y = (u32)f2bf(e2) | ((u32)f2bf(e3) << 16);
          *(uint2*)(qtb + (size_t)m * Nc + n0) = pv;
        }
    }
  }
}

// ---------------------------------------------------------------------------
// kk_inp: per bh, C[128 x 192] = qf_t . [qf_t | vbt]^T over n (K = 1024).
// Double-buffered, counted vmcnt (4 loads/wave batch). 384 thr, 6 waves.
// ---------------------------------------------------------------------------
__global__ __launch_bounds__(384) void kk_inp_kernel(
    const u16* __restrict__ qft, const u16* __restrict__ vbt,
    float* __restrict__ kk, float* __restrict__ inp) {
  __shared__ __align__(16) u16 SH[24576];
  const int t = threadIdx.x, bh = blockIdx.x;
  const int w = t >> 6, lane = t & 63, ln = lane & 15, kg = lane >> 4;
  const int wr = w / 3, wc = w % 3;
  const u16* qg = qft + (size_t)bh * Mc * Nc;   // [m][n]
  const u16* vg = vbt + (size_t)bh * 64 * Nc;   // [d][n]
  const int rr = lane >> 3;
  const int cs = ((lane & 7) ^ rr) << 3;
  f32x4 acc[4][4];
#pragma unroll
  for (int i = 0; i < 4; ++i)
#pragma unroll
    for (int j = 0; j < 4; ++j) acc[i][j] = fzero();

  auto stage = [&](int kt, int buf) {
    u16* Atl = SH + buf * 12288;
    u16* Vtl = Atl + 8192;
    const int n0 = kt * 64;
#pragma unroll
    for (int q = 0; q < 4; ++q) {
      const int idx = w * 4 + q;
      if (idx < 16) {
        __builtin_amdgcn_global_load_lds(
            (const __attribute__((address_space(1))) void*)(
                qg + (size_t)(idx * 8 + rr) * Nc + n0 + cs),
            (__attribute__((address_space(3))) void*)(Atl + idx * 8 * 64), 16,
            0, 0);
      } else {
        __builtin_amdgcn_global_load_lds(
            (const __attribute__((address_space(1))) void*)(
                vg + (size_t)((idx - 16) * 8 + rr) * Nc + n0 + cs),
            (__attribute__((address_space(3))) void*)(Vtl + (idx - 16) * 8 * 64),
            16, 0, 0);
      }
    }
  };

  stage(0, 0);
  int cur = 0;
  for (int kt = 0; kt < 16; ++kt) {
    if (kt < 15) {
      stage(kt + 1, cur ^ 1);
      WAIT_VM(4);
    } else {
      WAIT_VM(0);
    }
    BAR_RAW();
    const u16* Atl = SH + cur * 12288;
    const u16* Vtl = Atl + 8192;
#pragma unroll
    for (int ks = 0; ks < 2; ++ks) {
      const int cb = ks * 32 + kg * 8;
      bf16x8 af[4], bf[4];
#pragma unroll
      for (int i = 0; i < 4; ++i)
        af[i] = *(const bf16x8*)(Atl + (wr * 64 + i * 16 + ln) * 64 +
                                 SWZ_COL(cb, ln));
      if (wc < 2) {
#pragma unroll
        for (int j = 0; j < 4; ++j)
          bf[j] = *(const bf16x8*)(Atl + (wc * 64 + j * 16 + ln) * 64 +
                                   SWZ_COL(cb, ln));
      } else {
#pragma unroll
        for (int j = 0; j < 4; ++j)
          bf[j] = *(const bf16x8*)(Vtl + (j * 16 + ln) * 64 + SWZ_COL(cb, ln));
      }
#pragma unroll
      for (int i = 0; i < 4; ++i)
#pragma unroll
        for (int j = 0; j < 4; ++j) acc[i][j] = mfma16(af[i], bf[j], acc[i][j]);
    }
    BAR_RAW();
    cur ^= 1;
  }
  if (wc < 2) {
    float* og = kk + (size_t)bh * Mc * Mc;
#pragma unroll
    for (int i = 0; i < 4; ++i)
#pragma unroll
      for (int j = 0; j < 4; ++j)
#pragma unroll
        for (int r = 0; r < 4; ++r)
          og[(size_t)(wr * 64 + i * 16 + kg * 4 + r) * Mc + wc * 64 + j * 16 +
             ln] = acc[i][j][r];
  } else {
    float* og = inp + (size_t)bh * Mc * HDc;
#pragma unroll
    for (int i = 0; i < 4; ++i)
#pragma unroll
      for (int j = 0; j < 4; ++j)
#pragma unroll
        for (int r = 0; r < 4; ++r)
          og[(size_t)(wr * 64 + i * 16 + kg * 4 + r) * HDc + j * 16 + ln] =
              acc[i][j][r];
  }
}

// ---------------------------------------------------------------------------
// solve: fused norm + kkl + ISTA, one block per (b,h), fp16 MFMA.
// ---------------------------------------------------------------------------
__global__ __launch_bounds__(256) void solve_kernel(
    const float* __restrict__ kk, const float* __restrict__ inp,
    const f16* __restrict__ lk16, const f16* __restrict__ lkT16,
    const float* __restrict__ lamp, const float* __restrict__ Lp,
    u16* __restrict__ xsst) {
  __shared__ __align__(16) f16 A1[128 * FS];
  __shared__ __align__(16) f16 B1[128 * FS];
  __shared__ float nrm[128], inr[128];
  __shared__ float rsum2[256];
  __shared__ float Lsh;
  const int t = threadIdx.x, bh = blockIdx.x;
  const int w = t >> 6, lane = t & 63, ln = lane & 15, kq = lane >> 4;
  const float* kkg = kk + (size_t)bh * 16384;
  if (t < 128) {
    float nm = fmaxf(sqrtf(kkg[t * 128 + t]), EPSC);
    nrm[t] = nm;
    inr[t] = 1.0f / nm;
  }
#pragma unroll
  for (int c = 0; c < 8; ++c) {
    int ch = c * 256 + t;
    int r = ch >> 4, q8 = (ch & 15) * 8;
    *(uint4*)&B1[r * FS + q8] = *(const uint4*)&lkT16[r * 128 + q8];
  }
  __syncthreads();
#pragma unroll
  for (int c = 0; c < 16; ++c) {
    int ch = c * 256 + t;
    int m = ch >> 5, p4 = (ch & 31) * 4;
    float4 v = *(const float4*)&kkg[m * 128 + p4];
    float im = inr[m];
    union { f16 h[4]; uint2 u; } z;
    z.h[0] = (f16)(v.x * im * inr[p4]);
    z.h[1] = (f16)(v.y * im * inr[p4 + 1]);
    z.h[2] = (f16)(v.z * im * inr[p4 + 2]);
    z.h[3] = (f16)(v.w * im * inr[p4 + 3]);
    *(uint2*)&A1[m * FS + p4] = z.u;
  }
  __syncthreads();
  {
    const int m = t & 127, hf = (t >> 7) * 64;
    float s = 0.f;
#pragma unroll 8
    for (int p = 0; p < 64; ++p) s += fabsf((float)A1[m * FS + hf + p]);
    rsum2[t] = s;
  }
  f32x4 t1a[2][8];
#pragma unroll
  for (int i = 0; i < 2; ++i)
#pragma unroll
    for (int j = 0; j < 8; ++j) t1a[i][j] = fzero();
  __syncthreads();
  if (t == 0) {
    float mx = 0.f;
    for (int i = 0; i < 128; ++i) mx = fmaxf(mx, rsum2[i] + rsum2[i + 128]);
    Lsh = mx + 1.0f;
  }
#pragma unroll
  for (int ks = 0; ks < 4; ++ks) {
    f16x8 a[2], b[8];
#pragma unroll
    for (int i = 0; i < 2; ++i)
      a[i] = *(const f16x8*)&A1[(w * 32 + i * 16 + ln) * FS + ks * 32 + kq * 8];
#pragma unroll
    for (int j = 0; j < 8; ++j)
      b[j] = *(const f16x8*)&B1[(j * 16 + ln) * FS + ks * 32 + kq * 8];
#pragma unroll
    for (int i = 0; i < 2; ++i)
#pragma unroll
      for (int j = 0; j < 8; ++j) t1a[i][j] = mfma16h(a[i], b[j], t1a[i][j]);
  }
  __syncthreads();
#pragma unroll
  for (int i = 0; i < 2; ++i)
#pragma unroll
    for (int j = 0; j < 8; ++j) {
      const int r = j * 16 + ln, p0 = w * 32 + i * 16 + kq * 4;
      union { f16 h[4]; uint2 u; } z;
      z.h[0] = (f16)t1a[i][j][0]; z.h[1] = (f16)t1a[i][j][1];
      z.h[2] = (f16)t1a[i][j][2]; z.h[3] = (f16)t1a[i][j][3];
      *(uint2*)&A1[r * FS + p0] = z.u;
    }
#pragma unroll
  for (int c = 0; c < 8; ++c) {
    int ch = c * 256 + t;
    int r = ch >> 4, q8 = (ch & 15) * 8;
    *(uint4*)&B1[r * FS + q8] = *(const uint4*)&lk16[r * 128 + q8];
  }
  __syncthreads();
  f32x4 kla[2][8];
#pragma unroll
  for (int i = 0; i < 2; ++i)
#pragma unroll
    for (int j = 0; j < 8; ++j) kla[i][j] = fzero();
#pragma unroll
  for (int ks = 0; ks < 4; ++ks) {
    f16x8 a[2], b[8];
#pragma unroll
    for (int i = 0; i < 2; ++i)
      a[i] = *(const f16x8*)&B1[(w * 32 + i * 16 + ln) * FS + ks * 32 + kq * 8];
#pragma unroll
    for (int j = 0; j < 8; ++j)
      b[j] = *(const f16x8*)&A1[(j * 16 + ln) * FS + ks * 32 + kq * 8];
#pragma unroll
    for (int i = 0; i < 2; ++i)
#pragma unroll
      for (int j = 0; j < 8; ++j) kla[i][j] = mfma16h(a[i], b[j], kla[i][j]);
  }
  __syncthreads();
#pragma unroll
  for (int i = 0; i < 2; ++i)
#pragma unroll
    for (int j = 0; j < 8; ++j)
#pragma unroll
      for (int r = 0; r < 4; ++r)
        B1[(w * 32 + i * 16 + kq * 4 + r) * FS + j * 16 + ln] =
            (f16)kla[i][j][r];
  const float lam = lamp[0] * 0.1f;
  const float Ll = Lsh / Lp[0];
  const float thr = lam / Ll;
  const float invLl = 1.0f / Ll;
  const float* ig = inp + (size_t)bh * 8192;
  float ri[2][4][4], xr[2][4][4];
#pragma unroll
  for (int i = 0; i < 2; ++i)
#pragma unroll
    for (int j = 0; j < 4; ++j)
#pragma unroll
      for (int r = 0; r < 4; ++r) {
        const int m = w * 32 + i * 16 + kq * 4 + r;
        const int d = j * 16 + ln;
        ri[i][j][r] = ig[m * 64 + d] * inr[m];
        xr[i][j][r] = softf(ri[i][j][r], lam);
      }
  __syncthreads();
#pragma unroll
  for (int i = 0; i < 2; ++i)
#pragma unroll
    for (int j = 0; j < 4; ++j) {
      const int d = j * 16 + ln, m0 = w * 32 + i * 16 + kq * 4;
      union { f16 h[4]; uint2 u; } z;
      z.h[0] = (f16)xr[i][j][0]; z.h[1] = (f16)xr[i][j][1];
      z.h[2] = (f16)xr[i][j][2]; z.h[3] = (f16)xr[i][j][3];
      *(uint2*)&A1[d * FS + m0] = z.u;
    }
  __syncthreads();
  for (int s = 0; s < NUM_STEP_C; ++s) {
    f32x4 acc[2][4];
#pragma unroll
    for (int i = 0; i < 2; ++i)
#pragma unroll
      for (int j = 0; j < 4; ++j) acc[i][j] = fzero();
#pragma unroll
    for (int ks = 0; ks < 4; ++ks) {
      f16x8 a[2], b[4];
#pragma unroll
      for (int i = 0; i < 2; ++i)
        a[i] = *(const f16x8*)&B1[(w * 32 + i * 16 + ln) * FS + ks * 32 + kq * 8];
#pragma unroll
      for (int j = 0; j < 4; ++j)
        b[j] = *(const f16x8*)&A1[(j * 16 + ln) * FS + ks * 32 + kq * 8];
#pragma unroll
      for (int i = 0; i < 2; ++i)
#pragma unroll
        for (int j = 0; j < 4; ++j) acc[i][j] = mfma16h(a[i], b[j], acc[i][j]);
    }
#pragma unroll
    for (int i = 0; i < 2; ++i)
#pragma unroll
      for (int j = 0; j < 4; ++j)
#pragma unroll
        for (int r = 0; r < 4; ++r)
          xr[i][j][r] =
              softf(xr[i][j][r] - (acc[i][j][r] - ri[i][j][r]) * invLl, thr);
    __syncthreads();
#pragma unroll
    for (int i = 0; i < 2; ++i)
#pragma unroll
      for (int j = 0; j < 4; ++j) {
        const int d = j * 16 + ln, m0 = w * 32 + i * 16 + kq * 4;
        union { f16 h[4]; uint2 u; } z;
        z.h[0] = (f16)xr[i][j][0]; z.h[1] = (f16)xr[i][j][1];
        z.h[2] = (f16)xr[i][j][2]; z.h[3] = (f16)xr[i][j][3];
        *(uint2*)&A1[d * FS + m0] = z.u;
      }
    __syncthreads();
  }
  u16* og = xsst + (size_t)bh * 8192;
#pragma unroll
  for (int i = 0; i < 2; ++i)
#pragma unroll
    for (int j = 0; j < 4; ++j) {
      const int d = j * 16 + ln, m0 = w * 32 + i * 16 + kq * 4;
      uint2 pv;
      pv.x = (u32)f2bf(xr[i][j][0] * inr[m0]) |
             ((u32)f2bf(xr[i][j][1] * inr[m0 + 1]) << 16);
      pv.y = (u32)f2bf(xr[i][j][2] * inr[m0 + 2]) |
             ((u32)f2bf(xr[i][j][3] * inr[m0 + 3]) << 16);
      *(uint2*)&og[d * 128 + m0] = pv;
    }
}

// ---------------------------------------------------------------------------
// pvout: attn_bf[b*N+n][h*64+d] = sum_m qf_t[bh][m][n] * xss_t[bh][d][m]
// ---------------------------------------------------------------------------
__global__ __launch_bounds__(256) void pvout_kernel(
    const u16* __restrict__ qft, const u16* __restrict__ xsst,
    u16* __restrict__ attn) {
  const int t = threadIdx.x;
  const int bh = blockIdx.x, nt = blockIdx.y;
  const int b = bh / Hc, h = bh % Hc;
  const int w = t >> 6, lane = t & 63, ln = lane & 15, kg = lane >> 4;
  const u16* qt = qft + (size_t)bh * Mc * Nc;   // [m][n]
  const u16* xg = xsst + (size_t)bh * HDc * Mc; // [d][m]
  f32x4 acc[2][4];
#pragma unroll
  for (int i = 0; i < 2; ++i)
#pragma unroll
    for (int j = 0; j < 4; ++j) acc[i][j] = fzero();
#pragma unroll
  for (int ks = 0; ks < 4; ++ks) {
    const int m8 = ks * 32 + kg * 8;
    bf16x8 af[2];
#pragma unroll
    for (int i = 0; i < 2; ++i) {
      const int n = nt * 128 + w * 32 + i * 16 + ln;
      const u16* p = qt + (size_t)m8 * Nc + n;
#pragma unroll
      for (int e = 0; e < 8; ++e) af[i][e] = (short)p[(size_t)e * Nc];
    }
    bf16x8 bf[4];
#pragma unroll
    for (int j = 0; j < 4; ++j)
      bf[j] = *(const bf16x8*)(xg + (size_t)(j * 16 + ln) * Mc + m8);
#pragma unroll
    for (int i = 0; i < 2; ++i)
#pragma unroll
      for (int j = 0; j < 4; ++j) acc[i][j] = mfma16(af[i], bf[j], acc[i][j]);
  }
#pragma unroll
  for (int i = 0; i < 2; ++i)
#pragma unroll
    for (int j = 0; j < 4; ++j)
#pragma unroll
      for (int r = 0; r < 4; ++r) {
        int n = nt * 128 + w * 32 + i * 16 + kg * 4 + r;
        attn[((size_t)(b * Nc + n)) * Cc + h * 64 + j * 16 + ln] =
            f2bf(acc[i][j][r]);
      }
}

// ---------------------------------------------------------------------------
// proj: out[i][j] = sum_k attn_bf[i][k] * pwbf[j][k] + bias[j]  (f32 out)
// SINGLE-buffered (32 KB LDS -> 5 blocks/CU), XCD-swizzled grid.
// ---------------------------------------------------------------------------
__global__ __launch_bounds__(256) void proj_kernel(
    const u16* __restrict__ abf, const u16* __restrict__ pwbf,
    const float* __restrict__ bias, float* __restrict__ out) {
  __shared__ __align__(16) u16 SH[16384];
  u16* Als = SH;
  u16* Bls = SH + 8192;
  const int t = threadIdx.x;
  const int hblk = blockIdx.x;
  const int lin = (hblk & 7) * 192 + (hblk >> 3);
  const int bi = lin / 6, bj = lin % 6;
  const int w = t >> 6, lane = t & 63, ln = lane & 15, kg = lane >> 4;
  const int wr = w >> 1, wc = w & 1;
  f32x4 acc[4][4];
#pragma unroll
  for (int i = 0; i < 4; ++i)
#pragma unroll
    for (int j = 0; j < 4; ++j) acc[i][j] = fzero();
  const u16* Ag = abf + (size_t)(bi * 128) * Cc;
  const u16* Bg = pwbf + (size_t)(bj * 128) * Cc;
  for (int k0 = 0; k0 < Cc; k0 += 64) {
    stage_swz(Ag + k0, Cc, Als, w, lane);
    stage_swz(Bg + k0, Cc, Bls, w, lane);
    __syncthreads();
#pragma unroll
    for (int ks = 0; ks < 2; ++ks) {
      const int cb = ks * 32 + kg * 8;
      bf16x8 af[4], bf[4];
#pragma unroll
      for (int i = 0; i < 4; ++i)
        af[i] = *(const bf16x8*)(Als + (wr * 64 + i * 16 + ln) * 64 +
                                 SWZ_COL(cb, ln));
#pragma unroll
      for (int j = 0; j < 4; ++j)
        bf[j] = *(const bf16x8*)(Bls + (wc * 64 + j * 16 + ln) * 64 +
                                 SWZ_COL(cb, ln));
#pragma unroll
      for (int i = 0; i < 4; ++i)
#pragma unroll
        for (int j = 0; j < 4; ++j) acc[i][j] = mfma16(af[i], bf[j], acc[i][j]);
    }
    __syncthreads();
  }
#pragma unroll
  for (int j = 0; j < 4; ++j) {
    const int gc = bj * 128 + wc * 64 + j * 16 + ln;
    const float bv = bias[gc];
#pragma unroll
    for (int i = 0; i < 4; ++i) {
      const int gr = bi * 128 + wr * 64 + i * 16 + kg * 4;
#pragma unroll
      for (int r = 0; r < 4; ++r)
        out[(size_t)(gr + r) * Cc + gc] = acc[i][j][r] + bv;
    }
  }
}

// ---------------------------------------------------------------------------
extern "C" void kernel_launch(void* const* d_in, const int* in_sizes, int n_in,
                              void* d_out, int out_size, void* d_ws,
                              size_t ws_size, hipStream_t stream) {
  const float* x = (const float*)d_in[0];
  const float* qkv_w = (const float*)d_in[1];
  const float* proj_w = (const float*)d_in[2];
  const float* proj_b = (const float*)d_in[3];
  const float* rand_matrix = (const float*)d_in[4];
  const float* learned_k = (const float*)d_in[5];
  const float* learned_lam = (const float*)d_in[6];
  const float* learned_L = (const float*)d_in[7];
  float* out = (float*)d_out;

  const size_t SX = 25165824;   // x_bf / attn_bf (aliased)
  const size_t SQF = 50331648;  // qf_t
  const size_t SVT = 25165824;  // vb_t
  const size_t SXT = 3145728;   // xss_t
  const size_t SW = 1179648;    // w_bf
  const size_t SPW = 589824;    // pw_bf
  const size_t SRT = 98304;     // rand_t
  const size_t SLK = 16384;     // lk16 / lkT16 (f16, counted as u16 elems)
  const size_t U16TOT = SX + SQF + SVT + SXT + SW + SPW + SRT + 2 * SLK;
  const size_t SKK = 6291456, SIN = 3145728;
  const size_t need = U16TOT * 2 + (SKK + SIN) * 4;
  if (ws_size < need) return;  // graceful fail rather than OOB crash

  u16* xbf = (u16*)d_ws;
  u16* qft = xbf + SX;
  u16* vbt = qft + SQF;
  u16* xsst = vbt + SVT;
  u16* wbf = xsst + SXT;
  u16* pwbf = wbf + SW;
  u16* randt = pwbf + SPW;
  f16* lk16 = (f16*)(randt + SRT);
  f16* lkT16 = lk16 + SLK;
  float* kkf = (float*)(lkT16 + SLK);
  float* inpf = kkf + SKK;
  u16* attnbf = xbf;  // alias: x_bf dead after qkv

  prep_kernel<<<2048, 256, 0, stream>>>(x, qkv_w, proj_w, rand_matrix,
                                        learned_k, xbf, wbf, pwbf, randt,
                                        lk16, lkT16);
  qkv_qf_kernel<<<3072, 256, 0, stream>>>(xbf, wbf, randt, qft, vbt);
  kk_inp_kernel<<<Bc * Hc, 384, 0, stream>>>(qft, vbt, kkf, inpf);
  solve_kernel<<<Bc * Hc, 256, 0, stream>>>(kkf, inpf, lk16, lkT16,
                                            learned_lam, learned_L, xsst);
  pvout_kernel<<<dim3(Bc * Hc, Nc / 128), 256, 0, stream>>>(qft, xsst, attnbf);
  proj_kernel<<<1536, 256, 0, stream>>>(attnbf, pwbf, proj_b, out);
}

// Round 12
// 374.845 us; speedup vs baseline: 1.1780x; 1.1780x over previous
//
#include <hip/hip_runtime.h>
#include <math.h>

typedef unsigned short u16;
typedef unsigned int u32;
typedef _Float16 f16;
typedef __attribute__((ext_vector_type(8))) short bf16x8;
typedef __attribute__((ext_vector_type(8))) _Float16 f16x8;
typedef __attribute__((ext_vector_type(4))) float f32x4;

constexpr int Bc = 32, Nc = 1024, Cc = 768, Hc = 12, HDc = 64, Mc = 128;
constexpr int NUM_STEP_C = 8;
constexpr float QSCALE = 0.35355339059327376f;      // 8^-0.5
constexpr float INV_SQRT_M = 0.088388347648318447f; // 1/sqrt(128)
constexpr float EPSC = 1e-12f;
constexpr int FS = 136;  // f16 LDS row stride (16B-aligned, banks +4 mod 32)

__device__ __forceinline__ float softf(float z, float thr) {
  float az = fabsf(z) - thr;
  float g = 0.5f * az * (1.0f + erff(az * 0.70710678118654752f));
  return (z > 0.f) ? g : ((z < 0.f) ? -g : 0.f);
}

__device__ __forceinline__ u16 f2bf(float f) {
  u32 u = __float_as_uint(f);
  u += 0x7fffu + ((u >> 16) & 1u);
  return (u16)(u >> 16);
}

__device__ __forceinline__ f32x4 fzero() {
  f32x4 z; z[0] = 0.f; z[1] = 0.f; z[2] = 0.f; z[3] = 0.f; return z;
}

__device__ __forceinline__ f32x4 mfma16(bf16x8 a, bf16x8 b, f32x4 c) {
  return __builtin_amdgcn_mfma_f32_16x16x32_bf16(a, b, c, 0, 0, 0);
}
__device__ __forceinline__ f32x4 mfma16h(f16x8 a, f16x8 b, f32x4 c) {
  return __builtin_amdgcn_mfma_f32_16x16x32_f16(a, b, c, 0, 0, 0);
}

// Swizzled read offset within a [*][64]-u16 LDS tile: col(u16) XOR'ed by row
#define SWZ_COL(col, row) ((col) ^ (((row) & 7) << 3))

// Stage 32 rows x 64 u16 of a row-major (ld elems) global tile into linear
// LDS [.][64]; inverse swizzle pre-applied to the GLOBAL source (rule #21).
__device__ __forceinline__ void stage_swz(const u16* __restrict__ g, int ld,
                                          u16* lds, int w, int lane) {
  const int rr = lane >> 3;                 // 0..7 row within 8-row call
  const int cs = ((lane & 7) ^ rr) << 3;    // pre-swizzled col (u16)
#pragma unroll
  for (int c = 0; c < 4; ++c) {
    const int r0 = w * 32 + c * 8;
    __builtin_amdgcn_global_load_lds(
        (const __attribute__((address_space(1))) void*)(g + (size_t)(r0 + rr) * ld + cs),
        (__attribute__((address_space(3))) void*)(lds + r0 * 64), 16, 0, 0);
  }
}

// ---------------------------------------------------------------------------
// prep: f32 -> bf16 (x, qkv_w, proj_w), rand_matrix transpose, and
// learned_k -> fp16 (direct + transposed)
// ---------------------------------------------------------------------------
__global__ __launch_bounds__(256) void prep_kernel(
    const float* __restrict__ x, const float* __restrict__ qw,
    const float* __restrict__ pw, const float* __restrict__ rnd,
    const float* __restrict__ lkf, u16* __restrict__ xbf,
    u16* __restrict__ wbf, u16* __restrict__ pwbf, u16* __restrict__ randt,
    f16* __restrict__ lk16, f16* __restrict__ lkT16) {
  const int NX8 = 3145728, NW8 = 147456, NP8 = 73728, NR = 98304;
  const int NK8 = 2048, NKT = 16384;
  const int total = NX8 + NW8 + NP8 + NR + NK8 + NKT;
  for (int idx = blockIdx.x * 256 + threadIdx.x; idx < total;
       idx += gridDim.x * 256) {
    if (idx < NX8 + NW8 + NP8) {
      const float* src; u16* dst; int k;
      if (idx < NX8) { src = x; dst = xbf; k = idx; }
      else if (idx < NX8 + NW8) { src = qw; dst = wbf; k = idx - NX8; }
      else { src = pw; dst = pwbf; k = idx - NX8 - NW8; }
      float4 a = *(const float4*)(src + (size_t)k * 8);
      float4 b = *(const float4*)(src + (size_t)k * 8 + 4);
      uint4 o;
      o.x = (u32)f2bf(a.x) | ((u32)f2bf(a.y) << 16);
      o.y = (u32)f2bf(a.z) | ((u32)f2bf(a.w) << 16);
      o.z = (u32)f2bf(b.x) | ((u32)f2bf(b.y) << 16);
      o.w = (u32)f2bf(b.z) | ((u32)f2bf(b.w) << 16);
      *(uint4*)(dst + (size_t)k * 8) = o;
    } else if (idx < NX8 + NW8 + NP8 + NR) {
      int k = idx - NX8 - NW8 - NP8;           // rand_t[h][m][d]
      int h = k >> 13, rem = k & 8191, m = rem >> 6, d = rem & 63;
      randt[k] = f2bf(rnd[(size_t)h * 8192 + d * 128 + m]);
    } else if (idx < NX8 + NW8 + NP8 + NR + NK8) {
      int k = idx - (NX8 + NW8 + NP8 + NR);    // 8-wide fp16 convert
      float4 a = *(const float4*)(lkf + (size_t)k * 8);
      float4 b = *(const float4*)(lkf + (size_t)k * 8 + 4);
      union { f16 h[8]; uint4 u; } z;
      z.h[0] = (f16)a.x; z.h[1] = (f16)a.y; z.h[2] = (f16)a.z; z.h[3] = (f16)a.w;
      z.h[4] = (f16)b.x; z.h[5] = (f16)b.y; z.h[6] = (f16)b.z; z.h[7] = (f16)b.w;
      *(uint4*)(lk16 + (size_t)k * 8) = z.u;
    } else {
      int k = idx - (NX8 + NW8 + NP8 + NR + NK8);  // lkT16[c][p] = lk[p][c]
      int c = k >> 7, p = k & 127;
      lkT16[k] = (f16)lkf[p * 128 + c];
    }
  }
}

// ---------------------------------------------------------------------------
// Fused QKV MFMA GEMM + qf epilogue. BK=64, 2-phase dbuf (round-8 proven),
// XCD-swizzled grid. bj<6: q -> qf_t; bj>=6: v -> vb_t.
// ---------------------------------------------------------------------------
__global__ __launch_bounds__(256) void qkv_qf_kernel(
    const u16* __restrict__ xbf, const u16* __restrict__ wbf,
    const u16* __restrict__ randt, u16* __restrict__ qft,
    u16* __restrict__ vbt) {
  __shared__ __align__(16) u16 SH[32768];
  const int t = threadIdx.x;
  const int hblk = blockIdx.x;
  const int lin = (hblk & 7) * 384 + (hblk >> 3);
  const int bi = lin / 12, bj = lin % 12;
  const int w = t >> 6, lane = t & 63, ln = lane & 15, kg = lane >> 4;
  const int wr = w >> 1, wc = w & 1;
  f32x4 acc[4][4];
#pragma unroll
  for (int i = 0; i < 4; ++i)
#pragma unroll
    for (int j = 0; j < 4; ++j) acc[i][j] = fzero();
  const u16* Ag = xbf + (size_t)(bi * 128) * Cc;
  const u16* Bg = wbf + (size_t)(bj * 128) * Cc;
  stage_swz(Ag, Cc, SH, w, lane);
  stage_swz(Bg, Cc, SH + 8192, w, lane);
  __syncthreads();
  int cur = 0;
  for (int tt = 0; tt < 12; ++tt) {
    if (tt < 11) {
      stage_swz(Ag + (tt + 1) * 64, Cc, SH + (cur ^ 1) * 16384, w, lane);
      stage_swz(Bg + (tt + 1) * 64, Cc, SH + 8192 + (cur ^ 1) * 16384, w, lane);
    }
    const u16* Als = SH + cur * 16384;
    const u16* Bls = SH + 8192 + cur * 16384;
#pragma unroll
    for (int ks = 0; ks < 2; ++ks) {
      const int cb = ks * 32 + kg * 8;
      bf16x8 af[4], bf[4];
#pragma unroll
      for (int i = 0; i < 4; ++i)
        af[i] = *(const bf16x8*)(Als + (wr * 64 + i * 16 + ln) * 64 +
                                 SWZ_COL(cb, ln));
#pragma unroll
      for (int j = 0; j < 4; ++j)
        bf[j] = *(const bf16x8*)(Bls + (wc * 64 + j * 16 + ln) * 64 +
                                 SWZ_COL(cb, ln));
#pragma unroll
      for (int i = 0; i < 4; ++i)
#pragma unroll
        for (int j = 0; j < 4; ++j) acc[i][j] = mfma16(af[i], bf[j], acc[i][j]);
    }
    __syncthreads();
    cur ^= 1;
  }
  const int b = bi >> 3;
  const int ntile = (bi & 7) * 128;
  if (bj >= 6) {
    const int h = (bj - 6) * 2 + wc;
    u16* vt = vbt + ((size_t)(b * Hc + h) * 64) * 1024;
#pragma unroll
    for (int i = 0; i < 4; ++i)
#pragma unroll
      for (int j = 0; j < 4; ++j) {
        int d = j * 16 + ln;
        int n0 = ntile + wr * 64 + i * 16 + kg * 4;
        uint2 pv;
        pv.x = (u32)f2bf(acc[i][j][0]) | ((u32)f2bf(acc[i][j][1]) << 16);
        pv.y = (u32)f2bf(acc[i][j][2]) | ((u32)f2bf(acc[i][j][3]) << 16);
        *(uint2*)(vt + (size_t)d * 1024 + n0) = pv;
      }
  } else {
#pragma unroll
    for (int i = 0; i < 4; ++i)
#pragma unroll
      for (int j = 0; j < 4; ++j) acc[i][j] *= QSCALE;
    float hn[4][4];
#pragma unroll
    for (int i = 0; i < 4; ++i)
#pragma unroll
      for (int r = 0; r < 4; ++r) {
        float s = acc[i][0][r] * acc[i][0][r] + acc[i][1][r] * acc[i][1][r] +
                  acc[i][2][r] * acc[i][2][r] + acc[i][3][r] * acc[i][3][r];
        s += __shfl_xor(s, 1); s += __shfl_xor(s, 2);
        s += __shfl_xor(s, 4); s += __shfl_xor(s, 8);
        hn[i][r] = 0.5f * s;
      }
    u16* Qls = SH;
#pragma unroll
    for (int i = 0; i < 4; ++i)
#pragma unroll
      for (int j = 0; j < 4; ++j)
#pragma unroll
        for (int r = 0; r < 4; ++r)
          Qls[(size_t)(wc * 128 + wr * 64 + i * 16 + kg * 4 + r) * 72 +
              j * 16 + ln] = f2bf(acc[i][j][r]);
    __syncthreads();
    const int hq = bj * 2 + (w & 1);
    const int r0q = (w >> 1) * 64;
    const u16* rt = randt + (size_t)hq * Mc * HDc;  // [m][64]
    u16* qtb = qft + ((size_t)(b * Hc + hq) * Mc) * Nc;  // [m][n]
    const u16* qsl = Qls + (size_t)(w & 1) * 128 * 72;
#pragma unroll
    for (int mh = 0; mh < 2; ++mh) {
      f32x4 a2[4][4];
#pragma unroll
      for (int i = 0; i < 4; ++i)
#pragma unroll
        for (int j = 0; j < 4; ++j) a2[i][j] = fzero();
#pragma unroll
      for (int ks = 0; ks < 2; ++ks) {
        bf16x8 af[4], bfr[4];
#pragma unroll
        for (int i = 0; i < 4; ++i)
          af[i] = *(const bf16x8*)(qsl + (size_t)(r0q + i * 16 + ln) * 72 +
                                   ks * 32 + kg * 8);
#pragma unroll
        for (int j = 0; j < 4; ++j)
          bfr[j] = *(const bf16x8*)(rt +
                                    (size_t)(mh * 64 + j * 16 + ln) * 64 +
                                    ks * 32 + kg * 8);
#pragma unroll
        for (int i = 0; i < 4; ++i)
#pragma unroll
          for (int j = 0; j < 4; ++j)
            a2[i][j] = mfma16(af[i], bfr[j], a2[i][j]);
      }
#pragma unroll
      for (int i = 0; i < 4; ++i)
#pragma unroll
        for (int j = 0; j < 4; ++j) {
          const int m = mh * 64 + j * 16 + ln;
          const int n0 = ntile + r0q + i * 16 + kg * 4;
          float e0 = __expf(a2[i][j][0] - hn[i][0]) * INV_SQRT_M;
          float e1 = __expf(a2[i][j][1] - hn[i][1]) * INV_SQRT_M;
          float e2 = __expf(a2[i][j][2] - hn[i][2]) * INV_SQRT_M;
          float e3 = __expf(a2[i][j][3] - hn[i][3]) * INV_SQRT_M;
          uint2 pv;
          pv.x = (u32)f2bf(e0) | ((u32)f2bf(e1) << 16);
          pv.y = (u32)f2bf(e2) | ((u32)f2bf(e3) << 16);
          *(uint2*)(qtb + (size_t)m * Nc + n0) = pv;
        }
    }
  }
}

// ---------------------------------------------------------------------------
// kk_inp: per bh, C[128 x 192] = qf_t . [qf_t | vbt]^T over n (K = 1024).
// 2-phase dbuf (round-8 proven). 384 thr, 6 waves.
// ---------------------------------------------------------------------------
__global__ __launch_bounds__(384) void kk_inp_kernel(
    const u16* __restrict__ qft, const u16* __restrict__ vbt,
    float* __restrict__ kk, float* __restrict__ inp) {
  __shared__ __align__(16) u16 SH[24576];
  const int t = threadIdx.x, bh = blockIdx.x;
  const int w = t >> 6, lane = t & 63, ln = lane & 15, kg = lane >> 4;
  const int wr = w / 3, wc = w % 3;
  const u16* qg = qft + (size_t)bh * Mc * Nc;   // [m][n]
  const u16* vg = vbt + (size_t)bh * 64 * Nc;   // [d][n]
  const int rr = lane >> 3;
  const int cs = ((lane & 7) ^ rr) << 3;
  f32x4 acc[4][4];
#pragma unroll
  for (int i = 0; i < 4; ++i)
#pragma unroll
    for (int j = 0; j < 4; ++j) acc[i][j] = fzero();

  auto stage = [&](int kt, int buf) {
    u16* Atl = SH + buf * 12288;
    u16* Vtl = Atl + 8192;
    const int n0 = kt * 64;
#pragma unroll
    for (int q = 0; q < 4; ++q) {
      const int idx = w * 4 + q;
      if (idx < 16) {
        __builtin_amdgcn_global_load_lds(
            (const __attribute__((address_space(1))) void*)(
                qg + (size_t)(idx * 8 + rr) * Nc + n0 + cs),
            (__attribute__((address_space(3))) void*)(Atl + idx * 8 * 64), 16,
            0, 0);
      } else {
        __builtin_amdgcn_global_load_lds(
            (const __attribute__((address_space(1))) void*)(
                vg + (size_t)((idx - 16) * 8 + rr) * Nc + n0 + cs),
            (__attribute__((address_space(3))) void*)(Vtl + (idx - 16) * 8 * 64),
            16, 0, 0);
      }
    }
  };

  stage(0, 0);
  __syncthreads();
  int cur = 0;
  for (int kt = 0; kt < 16; ++kt) {
    if (kt < 15) stage(kt + 1, cur ^ 1);
    const u16* Atl = SH + cur * 12288;
    const u16* Vtl = Atl + 8192;
#pragma unroll
    for (int ks = 0; ks < 2; ++ks) {
      const int cb = ks * 32 + kg * 8;
      bf16x8 af[4], bf[4];
#pragma unroll
      for (int i = 0; i < 4; ++i)
        af[i] = *(const bf16x8*)(Atl + (wr * 64 + i * 16 + ln) * 64 +
                                 SWZ_COL(cb, ln));
      if (wc < 2) {
#pragma unroll
        for (int j = 0; j < 4; ++j)
          bf[j] = *(const bf16x8*)(Atl + (wc * 64 + j * 16 + ln) * 64 +
                                   SWZ_COL(cb, ln));
      } else {
#pragma unroll
        for (int j = 0; j < 4; ++j)
          bf[j] = *(const bf16x8*)(Vtl + (j * 16 + ln) * 64 + SWZ_COL(cb, ln));
      }
#pragma unroll
      for (int i = 0; i < 4; ++i)
#pragma unroll
        for (int j = 0; j < 4; ++j) acc[i][j] = mfma16(af[i], bf[j], acc[i][j]);
    }
    __syncthreads();
    cur ^= 1;
  }
  if (wc < 2) {
    float* og = kk + (size_t)bh * Mc * Mc;
#pragma unroll
    for (int i = 0; i < 4; ++i)
#pragma unroll
      for (int j = 0; j < 4; ++j)
#pragma unroll
        for (int r = 0; r < 4; ++r)
          og[(size_t)(wr * 64 + i * 16 + kg * 4 + r) * Mc + wc * 64 + j * 16 +
             ln] = acc[i][j][r];
  } else {
    float* og = inp + (size_t)bh * Mc * HDc;
#pragma unroll
    for (int i = 0; i < 4; ++i)
#pragma unroll
      for (int j = 0; j < 4; ++j)
#pragma unroll
        for (int r = 0; r < 4; ++r)
          og[(size_t)(wr * 64 + i * 16 + kg * 4 + r) * HDc + j * 16 + ln] =
              acc[i][j][r];
  }
}

// ---------------------------------------------------------------------------
// solve: fused norm + kkl + ISTA + PV, one block per (b,h), fp16/bf16 MFMA.
// After ISTA, xss (bf16) is written into A1's u16 space [d][m]; PV loop
// computes attn_bf[b*N+n][h*64+d] = sum_m qf_t[m][n] * xss[m][d] directly.
// ---------------------------------------------------------------------------
__global__ __launch_bounds__(256) void solve_kernel(
    const float* __restrict__ kk, const float* __restrict__ inp,
    const f16* __restrict__ lk16, const f16* __restrict__ lkT16,
    const float* __restrict__ lamp, const float* __restrict__ Lp,
    const u16* __restrict__ qft, u16* __restrict__ attn) {
  __shared__ __align__(16) f16 A1[128 * FS];
  __shared__ __align__(16) f16 B1[128 * FS];
  __shared__ float nrm[128], inr[128];
  __shared__ float rsum2[256];
  __shared__ float Lsh;
  const int t = threadIdx.x, bh = blockIdx.x;
  const int w = t >> 6, lane = t & 63, ln = lane & 15, kq = lane >> 4;
  const float* kkg = kk + (size_t)bh * 16384;
  if (t < 128) {
    float nm = fmaxf(sqrtf(kkg[t * 128 + t]), EPSC);
    nrm[t] = nm;
    inr[t] = 1.0f / nm;
  }
#pragma unroll
  for (int c = 0; c < 8; ++c) {
    int ch = c * 256 + t;
    int r = ch >> 4, q8 = (ch & 15) * 8;
    *(uint4*)&B1[r * FS + q8] = *(const uint4*)&lkT16[r * 128 + q8];
  }
  __syncthreads();
#pragma unroll
  for (int c = 0; c < 16; ++c) {
    int ch = c * 256 + t;
    int m = ch >> 5, p4 = (ch & 31) * 4;
    float4 v = *(const float4*)&kkg[m * 128 + p4];
    float im = inr[m];
    union { f16 h[4]; uint2 u; } z;
    z.h[0] = (f16)(v.x * im * inr[p4]);
    z.h[1] = (f16)(v.y * im * inr[p4 + 1]);
    z.h[2] = (f16)(v.z * im * inr[p4 + 2]);
    z.h[3] = (f16)(v.w * im * inr[p4 + 3]);
    *(uint2*)&A1[m * FS + p4] = z.u;
  }
  __syncthreads();
  {
    const int m = t & 127, hf = (t >> 7) * 64;
    float s = 0.f;
#pragma unroll 8
    for (int p = 0; p < 64; ++p) s += fabsf((float)A1[m * FS + hf + p]);
    rsum2[t] = s;
  }
  f32x4 t1a[2][8];
#pragma unroll
  for (int i = 0; i < 2; ++i)
#pragma unroll
    for (int j = 0; j < 8; ++j) t1a[i][j] = fzero();
  __syncthreads();
  if (t == 0) {
    float mx = 0.f;
    for (int i = 0; i < 128; ++i) mx = fmaxf(mx, rsum2[i] + rsum2[i + 128]);
    Lsh = mx + 1.0f;
  }
#pragma unroll
  for (int ks = 0; ks < 4; ++ks) {
    f16x8 a[2], b[8];
#pragma unroll
    for (int i = 0; i < 2; ++i)
      a[i] = *(const f16x8*)&A1[(w * 32 + i * 16 + ln) * FS + ks * 32 + kq * 8];
#pragma unroll
    for (int j = 0; j < 8; ++j)
      b[j] = *(const f16x8*)&B1[(j * 16 + ln) * FS + ks * 32 + kq * 8];
#pragma unroll
    for (int i = 0; i < 2; ++i)
#pragma unroll
      for (int j = 0; j < 8; ++j) t1a[i][j] = mfma16h(a[i], b[j], t1a[i][j]);
  }
  __syncthreads();
#pragma unroll
  for (int i = 0; i < 2; ++i)
#pragma unroll
    for (int j = 0; j < 8; ++j) {
      const int r = j * 16 + ln, p0 = w * 32 + i * 16 + kq * 4;
      union { f16 h[4]; uint2 u; } z;
      z.h[0] = (f16)t1a[i][j][0]; z.h[1] = (f16)t1a[i][j][1];
      z.h[2] = (f16)t1a[i][j][2]; z.h[3] = (f16)t1a[i][j][3];
      *(uint2*)&A1[r * FS + p0] = z.u;
    }
#pragma unroll
  for (int c = 0; c < 8; ++c) {
    int ch = c * 256 + t;
    int r = ch >> 4, q8 = (ch & 15) * 8;
    *(uint4*)&B1[r * FS + q8] = *(const uint4*)&lk16[r * 128 + q8];
  }
  __syncthreads();
  f32x4 kla[2][8];
#pragma unroll
  for (int i = 0; i < 2; ++i)
#pragma unroll
    for (int j = 0; j < 8; ++j) kla[i][j] = fzero();
#pragma unroll
  for (int ks = 0; ks < 4; ++ks) {
    f16x8 a[2], b[8];
#pragma unroll
    for (int i = 0; i < 2; ++i)
      a[i] = *(const f16x8*)&B1[(w * 32 + i * 16 + ln) * FS + ks * 32 + kq * 8];
#pragma unroll
    for (int j = 0; j < 8; ++j)
      b[j] = *(const f16x8*)&A1[(j * 16 + ln) * FS + ks * 32 + kq * 8];
#pragma unroll
    for (int i = 0; i < 2; ++i)
#pragma unroll
      for (int j = 0; j < 8; ++j) kla[i][j] = mfma16h(a[i], b[j], kla[i][j]);
  }
  __syncthreads();
#pragma unroll
  for (int i = 0; i < 2; ++i)
#pragma unroll
    for (int j = 0; j < 8; ++j)
#pragma unroll
      for (int r = 0; r < 4; ++r)
        B1[(w * 32 + i * 16 + kq * 4 + r) * FS + j * 16 + ln] =
            (f16)kla[i][j][r];
  const float lam = lamp[0] * 0.1f;
  const float Ll = Lsh / Lp[0];
  const float thr = lam / Ll;
  const float invLl = 1.0f / Ll;
  const float* ig = inp + (size_t)bh * 8192;
  float ri[2][4][4], xr[2][4][4];
#pragma unroll
  for (int i = 0; i < 2; ++i)
#pragma unroll
    for (int j = 0; j < 4; ++j)
#pragma unroll
      for (int r = 0; r < 4; ++r) {
        const int m = w * 32 + i * 16 + kq * 4 + r;
        const int d = j * 16 + ln;
        ri[i][j][r] = ig[m * 64 + d] * inr[m];
        xr[i][j][r] = softf(ri[i][j][r], lam);
      }
  __syncthreads();
#pragma unroll
  for (int i = 0; i < 2; ++i)
#pragma unroll
    for (int j = 0; j < 4; ++j) {
      const int d = j * 16 + ln, m0 = w * 32 + i * 16 + kq * 4;
      union { f16 h[4]; uint2 u; } z;
      z.h[0] = (f16)xr[i][j][0]; z.h[1] = (f16)xr[i][j][1];
      z.h[2] = (f16)xr[i][j][2]; z.h[3] = (f16)xr[i][j][3];
      *(uint2*)&A1[d * FS + m0] = z.u;
    }
  __syncthreads();
  for (int s = 0; s < NUM_STEP_C; ++s) {
    f32x4 acc[2][4];
#pragma unroll
    for (int i = 0; i < 2; ++i)
#pragma unroll
      for (int j = 0; j < 4; ++j) acc[i][j] = fzero();
#pragma unroll
    for (int ks = 0; ks < 4; ++ks) {
      f16x8 a[2], b[4];
#pragma unroll
      for (int i = 0; i < 2; ++i)
        a[i] = *(const f16x8*)&B1[(w * 32 + i * 16 + ln) * FS + ks * 32 + kq * 8];
#pragma unroll
      for (int j = 0; j < 4; ++j)
        b[j] = *(const f16x8*)&A1[(j * 16 + ln) * FS + ks * 32 + kq * 8];
#pragma unroll
      for (int i = 0; i < 2; ++i)
#pragma unroll
        for (int j = 0; j < 4; ++j) acc[i][j] = mfma16h(a[i], b[j], acc[i][j]);
    }
#pragma unroll
    for (int i = 0; i < 2; ++i)
#pragma unroll
      for (int j = 0; j < 4; ++j)
#pragma unroll
        for (int r = 0; r < 4; ++r)
          xr[i][j][r] =
              softf(xr[i][j][r] - (acc[i][j][r] - ri[i][j][r]) * invLl, thr);
    __syncthreads();
#pragma unroll
    for (int i = 0; i < 2; ++i)
#pragma unroll
      for (int j = 0; j < 4; ++j) {
        const int d = j * 16 + ln, m0 = w * 32 + i * 16 + kq * 4;
        union { f16 h[4]; uint2 u; } z;
        z.h[0] = (f16)xr[i][j][0]; z.h[1] = (f16)xr[i][j][1];
        z.h[2] = (f16)xr[i][j][2]; z.h[3] = (f16)xr[i][j][3];
        *(uint2*)&A1[d * FS + m0] = z.u;
      }
    __syncthreads();
  }
  // ---- xss (bf16) -> A1 u16 space [d][m]; then fused PV ----
  u16* A1u = (u16*)A1;
#pragma unroll
  for (int i = 0; i < 2; ++i)
#pragma unroll
    for (int j = 0; j < 4; ++j) {
      const int d = j * 16 + ln, m0 = w * 32 + i * 16 + kq * 4;
      uint2 pv;
      pv.x = (u32)f2bf(xr[i][j][0] * inr[m0]) |
             ((u32)f2bf(xr[i][j][1] * inr[m0 + 1]) << 16);
      pv.y = (u32)f2bf(xr[i][j][2] * inr[m0 + 2]) |
             ((u32)f2bf(xr[i][j][3] * inr[m0 + 3]) << 16);
      *(uint2*)&A1u[d * FS + m0] = pv;
    }
  __syncthreads();
  const u16* qt = qft + (size_t)bh * Mc * Nc;  // [m][n]
  const int b = bh / Hc, h = bh % Hc;
  for (int nt = 0; nt < 8; ++nt) {
    f32x4 pacc[2][4];
#pragma unroll
    for (int i = 0; i < 2; ++i)
#pragma unroll
      for (int j = 0; j < 4; ++j) pacc[i][j] = fzero();
#pragma unroll
    for (int ks = 0; ks < 4; ++ks) {
      const int m8 = ks * 32 + kq * 8;
      bf16x8 af[2];
#pragma unroll
      for (int i = 0; i < 2; ++i) {
        const int n = nt * 128 + w * 32 + i * 16 + ln;
        const u16* p = qt + (size_t)m8 * Nc + n;
#pragma unroll
        for (int e = 0; e < 8; ++e) af[i][e] = (short)p[(size_t)e * Nc];
      }
      bf16x8 bf[4];
#pragma unroll
      for (int j = 0; j < 4; ++j)
        bf[j] = *(const bf16x8*)&A1u[(j * 16 + ln) * FS + m8];
#pragma unroll
      for (int i = 0; i < 2; ++i)
#pragma unroll
        for (int j = 0; j < 4; ++j)
          pacc[i][j] = mfma16(af[i], bf[j], pacc[i][j]);
    }
#pragma unroll
    for (int i = 0; i < 2; ++i)
#pragma unroll
      for (int j = 0; j < 4; ++j)
#pragma unroll
        for (int r = 0; r < 4; ++r) {
          int n = nt * 128 + w * 32 + i * 16 + kq * 4 + r;
          attn[((size_t)(b * Nc + n)) * Cc + h * 64 + j * 16 + ln] =
              f2bf(pacc[i][j][r]);
        }
  }
}

// ---------------------------------------------------------------------------
// proj: out[i][j] = sum_k attn_bf[i][k] * pwbf[j][k] + bias[j]  (f32 out)
// 2-phase dbuf (round-8 proven), XCD-swizzled grid.
// ---------------------------------------------------------------------------
__global__ __launch_bounds__(256) void proj_kernel(
    const u16* __restrict__ abf, const u16* __restrict__ pwbf,
    const float* __restrict__ bias, float* __restrict__ out) {
  __shared__ __align__(16) u16 SH[32768];
  const int t = threadIdx.x;
  const int hblk = blockIdx.x;
  const int lin = (hblk & 7) * 192 + (hblk >> 3);
  const int bi = lin / 6, bj = lin % 6;
  const int w = t >> 6, lane = t & 63, ln = lane & 15, kg = lane >> 4;
  const int wr = w >> 1, wc = w & 1;
  f32x4 acc[4][4];
#pragma unroll
  for (int i = 0; i < 4; ++i)
#pragma unroll
    for (int j = 0; j < 4; ++j) acc[i][j] = fzero();
  const u16* Ag = abf + (size_t)(bi * 128) * Cc;
  const u16* Bg = pwbf + (size_t)(bj * 128) * Cc;
  stage_swz(Ag, Cc, SH, w, lane);
  stage_swz(Bg, Cc, SH + 8192, w, lane);
  __syncthreads();
  int cur = 0;
  for (int tt = 0; tt < 12; ++tt) {
    if (tt < 11) {
      stage_swz(Ag + (tt + 1) * 64, Cc, SH + (cur ^ 1) * 16384, w, lane);
      stage_swz(Bg + (tt + 1) * 64, Cc, SH + 8192 + (cur ^ 1) * 16384, w, lane);
    }
    const u16* Als = SH + cur * 16384;
    const u16* Bls = SH + 8192 + cur * 16384;
#pragma unroll
    for (int ks = 0; ks < 2; ++ks) {
      const int cb = ks * 32 + kg * 8;
      bf16x8 af[4], bf[4];
#pragma unroll
      for (int i = 0; i < 4; ++i)
        af[i] = *(const bf16x8*)(Als + (wr * 64 + i * 16 + ln) * 64 +
                                 SWZ_COL(cb, ln));
#pragma unroll
      for (int j = 0; j < 4; ++j)
        bf[j] = *(const bf16x8*)(Bls + (wc * 64 + j * 16 + ln) * 64 +
                                 SWZ_COL(cb, ln));
#pragma unroll
      for (int i = 0; i < 4; ++i)
#pragma unroll
        for (int j = 0; j < 4; ++j) acc[i][j] = mfma16(af[i], bf[j], acc[i][j]);
    }
    __syncthreads();
    cur ^= 1;
  }
#pragma unroll
  for (int j = 0; j < 4; ++j) {
    const int gc = bj * 128 + wc * 64 + j * 16 + ln;
    const float bv = bias[gc];
#pragma unroll
    for (int i = 0; i < 4; ++i) {
      const int gr = bi * 128 + wr * 64 + i * 16 + kg * 4;
#pragma unroll
      for (int r = 0; r < 4; ++r)
        out[(size_t)(gr + r) * Cc + gc] = acc[i][j][r] + bv;
    }
  }
}

// ---------------------------------------------------------------------------
extern "C" void kernel_launch(void* const* d_in, const int* in_sizes, int n_in,
                              void* d_out, int out_size, void* d_ws,
                              size_t ws_size, hipStream_t stream) {
  const float* x = (const float*)d_in[0];
  const float* qkv_w = (const float*)d_in[1];
  const float* proj_w = (const float*)d_in[2];
  const float* proj_b = (const float*)d_in[3];
  const float* rand_matrix = (const float*)d_in[4];
  const float* learned_k = (const float*)d_in[5];
  const float* learned_lam = (const float*)d_in[6];
  const float* learned_L = (const float*)d_in[7];
  float* out = (float*)d_out;

  const size_t SX = 25165824;   // x_bf / attn_bf (aliased)
  const size_t SQF = 50331648;  // qf_t
  const size_t SVT = 25165824;  // vb_t
  const size_t SW = 1179648;    // w_bf
  const size_t SPW = 589824;    // pw_bf
  const size_t SRT = 98304;     // rand_t
  const size_t SLK = 16384;     // lk16 / lkT16 (f16, counted as u16 elems)
  const size_t U16TOT = SX + SQF + SVT + SW + SPW + SRT + 2 * SLK;
  const size_t SKK = 6291456, SIN = 3145728;
  const size_t need = U16TOT * 2 + (SKK + SIN) * 4;
  if (ws_size < need) return;  // graceful fail rather than OOB crash

  u16* xbf = (u16*)d_ws;
  u16* qft = xbf + SX;
  u16* vbt = qft + SQF;
  u16* wbf = vbt + SVT;
  u16* pwbf = wbf + SW;
  u16* randt = pwbf + SPW;
  f16* lk16 = (f16*)(randt + SRT);
  f16* lkT16 = lk16 + SLK;
  float* kkf = (float*)(lkT16 + SLK);
  float* inpf = kkf + SKK;
  u16* attnbf = xbf;  // alias: x_bf dead after qkv

  prep_kernel<<<2048, 256, 0, stream>>>(x, qkv_w, proj_w, rand_matrix,
                                        learned_k, xbf, wbf, pwbf, randt,
                                        lk16, lkT16);
  qkv_qf_kernel<<<3072, 256, 0, stream>>>(xbf, wbf, randt, qft, vbt);
  kk_inp_kernel<<<Bc * Hc, 384, 0, stream>>>(qft, vbt, kkf, inpf);
  solve_kernel<<<Bc * Hc, 256, 0, stream>>>(kkf, inpf, lk16, lkT16,
                                            learned_lam, learned_L, qft,
                                            attnbf);
  proj_kernel<<<1536, 256, 0, stream>>>(attnbf, pwbf, proj_b, out);
}